// Round 17
// baseline (278.494 us; speedup 1.0000x reference)
//
#include <hip/hip_runtime.h>

// ---------------------------------------------------------------------------
// Types
// ---------------------------------------------------------------------------
typedef __bf16 bf16x8 __attribute__((ext_vector_type(8)));
typedef float f32x4 __attribute__((ext_vector_type(4)));
typedef unsigned short ushort_t;

#define THREADS 256      // 4-wave path (disc_h / final / adapter_down / disc_loss)

__device__ __forceinline__ unsigned short f2bf(float f) {
  unsigned int u = __builtin_bit_cast(unsigned int, f);
  u += 0x7fffu + ((u >> 16) & 1u);   // RNE (no NaN in this data)
  return (unsigned short)(u >> 16);
}

__device__ __forceinline__ float bf2f(ushort_t u) {
  unsigned int v = ((unsigned int)u) << 16;
  return __builtin_bit_cast(float, v);
}

__device__ __forceinline__ void gload_lds16(const ushort_t* g, ushort_t* l) {
  __builtin_amdgcn_global_load_lds(
      (const __attribute__((address_space(1))) void*)g,
      (__attribute__((address_space(3))) void*)l, 16, 0, 0);
}

// counted vmcnt wait. NO sched_barrier (m141/R8 lesson).
template <int N>
__device__ __forceinline__ void wait_vmcnt() {
  if constexpr (N == 0)
    asm volatile("s_waitcnt vmcnt(0)" ::: "memory");
  else if constexpr (N == 4)
    asm volatile("s_waitcnt vmcnt(4)" ::: "memory");
  else if constexpr (N == 6)
    asm volatile("s_waitcnt vmcnt(6)" ::: "memory");
}

__device__ __forceinline__ void block_barrier() {
  asm volatile("" ::: "memory");
  __builtin_amdgcn_s_barrier();
  asm volatile("" ::: "memory");
}

// inline argmin over losses[e*8 + sample], e = 0..7
__device__ __forceinline__ int argmin8(const float* __restrict__ losses,
                                       int sample) {
  float best = losses[sample];
  int bi = 0;
#pragma unroll
  for (int e = 1; e < 8; ++e) {
    float v = losses[e * 8 + sample];
    if (v < best) { best = v; bi = e; }
  }
  return bi;
}

// ---------------------------------------------------------------------------
// Fused prologue: weight transposes + x cast in ONE kernel.  block (32,8).
//   [0,2048)    Wd1  -> Wd1T   [2048,4096) Wd2 -> Wd2T
//   [4096,5120) Wb   -> WbT    [5120,5632) Wad -> WadT
//   [5632,6144) Wau  -> WauT   [6144,8192) cast x (f32 -> bf16)
// Block 0 also zeroes losses[64].
// ---------------------------------------------------------------------------
__global__ void transpose_all_kernel(
    const float* __restrict__ Wd1, const float* __restrict__ Wd2,
    const float* __restrict__ Wb, const float* __restrict__ Wad,
    const float* __restrict__ Wau, const float4* __restrict__ x4,
    ushort_t* __restrict__ Wd1T, ushort_t* __restrict__ Wd2T,
    ushort_t* __restrict__ WbT, ushort_t* __restrict__ WadT,
    ushort_t* __restrict__ WauT, ushort4* __restrict__ x_bf4,
    float* __restrict__ losses) {
  __shared__ float t[32][33];
  int b = blockIdx.x;
  int tx = threadIdx.x, ty = threadIdx.y;
  int ft = ty * 32 + tx;
  if (b == 0 && ft < 64) losses[ft] = 0.f;

  if (b >= 6144) {
    int base = (b - 6144) * 2048 + ft;
#pragma unroll
    for (int i = 0; i < 8; ++i) {
      float4 v = x4[base + i * 256];
      ushort4 o;
      o.x = f2bf(v.x); o.y = f2bf(v.y); o.z = f2bf(v.z); o.w = f2bf(v.w);
      x_bf4[base + i * 256] = o;
    }
    return;
  }

  const float* src;
  ushort_t* dst;
  int R, C, z, cx, ry;
  if (b < 2048) {
    src = Wd1; dst = Wd1T; R = 1024; C = 256;
    z = b >> 8; int rem = b & 255; cx = rem & 7; ry = rem >> 3;
  } else if (b < 4096) {
    int bb = b - 2048;
    src = Wd2; dst = Wd2T; R = 256; C = 1024;
    z = bb >> 8; int rem = bb & 255; cx = rem & 31; ry = rem >> 5;
  } else if (b < 5120) {
    int bb = b - 4096;
    src = Wb; dst = WbT; R = 1024; C = 1024;
    z = 0; cx = bb & 31; ry = bb >> 5;
  } else if (b < 5632) {
    int bb = b - 5120;
    src = Wad; dst = WadT; R = 1024; C = 64;
    z = bb >> 6; int rem = bb & 63; cx = rem & 1; ry = rem >> 1;
  } else {
    int bb = b - 5632;
    src = Wau; dst = WauT; R = 64; C = 1024;
    z = bb >> 6; int rem = bb & 63; cx = rem & 31; ry = rem >> 5;
  }
  size_t zoff = (size_t)z * R * C;
  src += zoff; dst += zoff;
  int c0 = cx * 32, r0 = ry * 32;
#pragma unroll
  for (int i = 0; i < 4; ++i)
    t[ty + 8 * i][tx] = src[(size_t)(r0 + ty + 8 * i) * C + c0 + tx];
  __syncthreads();
#pragma unroll
  for (int i = 0; i < 4; ++i)
    dst[(size_t)(c0 + ty + 8 * i) * R + r0 + tx] = f2bf(t[tx][ty + 8 * i]);
}

#define ACC_ZERO(acc, MM, NN)                        \
  _Pragma("unroll") for (int _i = 0; _i < MM; ++_i)  \
  _Pragma("unroll") for (int _j = 0; _j < NN; ++_j)  \
      acc[_i][_j] = (f32x4){0.f, 0.f, 0.f, 0.f};

// ---------------------------------------------------------------------------
// 4-slot XOR swizzle (R4/R7-proven conflict-free).
// LDS tile [ROWS][32] bf16; slot s of row holds global k-chunk s ^ ((row>>1)&3).
// ---------------------------------------------------------------------------
__device__ __forceinline__ int sw(int row) { return (row >> 1) & 3; }

__device__ __forceinline__ bf16x8 frag_sw(const ushort_t* lds, int row, int q) {
  int slot = q ^ sw(row);
  return *(const bf16x8*)(lds + (row * 4 + slot) * 8);
}

// Staging, templated on block size.  (BM+BN)*4/NT loads per thread per stage.
template <int BM, int BN, int NT>
__device__ __forceinline__ void stage_p(const ushort_t* __restrict__ A,
                                        size_t lda, int arow0,
                                        const ushort_t* __restrict__ BT,
                                        size_t ldb, int brow0, int k0,
                                        ushort_t* As, ushort_t* Bs, int tid) {
#pragma unroll
  for (int i = 0; i < BM * 4 / NT; ++i) {
    int c = tid + i * NT;
    int row = c >> 2, slot = c & 3;
    int g = slot ^ sw(row);
    gload_lds16(A + (size_t)(arow0 + row) * lda + k0 + g * 8, As + c * 8);
  }
#pragma unroll
  for (int i = 0; i < BN * 4 / NT; ++i) {
    int c = tid + i * NT;
    int row = c >> 2, slot = c & 3;
    int g = slot ^ sw(row);
    gload_lds16(BT + (size_t)(brow0 + row) * ldb + k0 + g * 8, Bs + c * 8);
  }
}

#define PIPE_LDS_BYTES ((3 * (256 * 32) + 3 * (128 * 32)) * 2)  // 73728
#define DL_LDS_BYTES   ((3 * (128 * 32) + 3 * (128 * 32)) * 2)  // 49152

// ===========================================================================
// PIPE PATH A (disc_h / final): 256 thr = 4 waves (2m x 2n), wave-tile
// 128x64, acc[8][4].  R14-measured best for deep-K (nt>=16).
// Per K-step: vmcnt(6) -> barrier -> stage(t+2) -> ds_read 12 frags ->
// setprio(1) 32 MFMA.
// ===========================================================================
template <int BM, int BN>
__device__ __forceinline__ void pipe_kloop84(const ushort_t* __restrict__ A,
                                             size_t lda, int arow0,
                                             const ushort_t* __restrict__ BT,
                                             size_t ldb, int brow0, int K,
                                             ushort_t* smem, int tid, int wm,
                                             int wn, f32x4 acc[8][4]) {
  constexpr int ASLOT = BM * 32, BSLOT = BN * 32;
  ushort_t* Asl = smem;
  ushort_t* Bsl = smem + 3 * ASLOT;
  int lane = tid & 63;
  int r = lane & 15, q = lane >> 4;
  int nt = K >> 5;
  stage_p<BM, BN, THREADS>(A, lda, arow0, BT, ldb, brow0, 0, Asl, Bsl, tid);
  if (nt > 1)
    stage_p<BM, BN, THREADS>(A, lda, arow0, BT, ldb, brow0, 32, Asl + ASLOT,
                             Bsl + BSLOT, tid);
  for (int t = 0; t < nt; ++t) {
    if (t + 1 < nt)
      wait_vmcnt<6>();
    else
      wait_vmcnt<0>();
    block_barrier();
    if (t + 2 < nt) {
      int s = (t + 2) % 3;
      stage_p<BM, BN, THREADS>(A, lda, arow0, BT, ldb, brow0, (t + 2) * 32,
                               Asl + s * ASLOT, Bsl + s * BSLOT, tid);
    }
    int cur = t % 3;
    const ushort_t* Ac = Asl + cur * ASLOT;
    const ushort_t* Bc = Bsl + cur * BSLOT;
    bf16x8 af[8], bg[4];
#pragma unroll
    for (int mi = 0; mi < 8; ++mi)
      af[mi] = frag_sw(Ac, wm * 128 + mi * 16 + r, q);
#pragma unroll
    for (int ni = 0; ni < 4; ++ni)
      bg[ni] = frag_sw(Bc, wn * 64 + ni * 16 + r, q);
    __builtin_amdgcn_s_setprio(1);
#pragma unroll
    for (int mi = 0; mi < 8; ++mi)
#pragma unroll
      for (int ni = 0; ni < 4; ++ni)
        acc[mi][ni] = __builtin_amdgcn_mfma_f32_16x16x32_bf16(
            af[mi], bg[ni], acc[mi][ni], 0, 0, 0);
    __builtin_amdgcn_s_setprio(0);
  }
  block_barrier();
}

// ===========================================================================
// PIPE PATH B (disc_loss): 256 thr = 4 waves (2m x 2n), wave-tile 64x64,
// acc[4][4], tile 128x128.  Ring-3 LDS 48 KB -> 3 blocks/CU: three
// INDEPENDENT pipelines per CU interleave their fill/drain (R10/R13 lesson
// pushed further for short-K nt=8).  4 loads/thread/stage -> vmcnt(4).
// ===========================================================================
template <int BM, int BN>
__device__ __forceinline__ void pipe_kloop44(const ushort_t* __restrict__ A,
                                             size_t lda, int arow0,
                                             const ushort_t* __restrict__ BT,
                                             size_t ldb, int brow0, int K,
                                             ushort_t* smem, int tid, int wm,
                                             int wn, f32x4 acc[4][4]) {
  constexpr int ASLOT = BM * 32, BSLOT = BN * 32;
  ushort_t* Asl = smem;
  ushort_t* Bsl = smem + 3 * ASLOT;
  int lane = tid & 63;
  int r = lane & 15, q = lane >> 4;
  int nt = K >> 5;
  stage_p<BM, BN, THREADS>(A, lda, arow0, BT, ldb, brow0, 0, Asl, Bsl, tid);
  if (nt > 1)
    stage_p<BM, BN, THREADS>(A, lda, arow0, BT, ldb, brow0, 32, Asl + ASLOT,
                             Bsl + BSLOT, tid);
  for (int t = 0; t < nt; ++t) {
    if (t + 1 < nt)
      wait_vmcnt<4>();
    else
      wait_vmcnt<0>();
    block_barrier();
    if (t + 2 < nt) {
      int s = (t + 2) % 3;
      stage_p<BM, BN, THREADS>(A, lda, arow0, BT, ldb, brow0, (t + 2) * 32,
                               Asl + s * ASLOT, Bsl + s * BSLOT, tid);
    }
    int cur = t % 3;
    const ushort_t* Ac = Asl + cur * ASLOT;
    const ushort_t* Bc = Bsl + cur * BSLOT;
    bf16x8 af[4], bg[4];
#pragma unroll
    for (int mi = 0; mi < 4; ++mi)
      af[mi] = frag_sw(Ac, wm * 64 + mi * 16 + r, q);
#pragma unroll
    for (int ni = 0; ni < 4; ++ni)
      bg[ni] = frag_sw(Bc, wn * 64 + ni * 16 + r, q);
    __builtin_amdgcn_s_setprio(1);
#pragma unroll
    for (int mi = 0; mi < 4; ++mi)
#pragma unroll
      for (int ni = 0; ni < 4; ++ni)
        acc[mi][ni] = __builtin_amdgcn_mfma_f32_16x16x32_bf16(
            af[mi], bg[ni], acc[mi][ni], 0, 0, 0);
    __builtin_amdgcn_s_setprio(0);
  }
  block_barrier();
}

// ---------------------------------------------------------------------------
// disc_h: h = relu(x @ Wd1_all + bd1_all), M=16384, N=2048, K=1024.
// grid 1024, 256 thr, XCD-chunked.  Output -> h[e][16384][256] (e = col>>8).
// ---------------------------------------------------------------------------
__global__ __launch_bounds__(THREADS, 2) void disc_h_kernel(
    const ushort_t* __restrict__ x_bf, const ushort_t* __restrict__ Wd1T,
    const float* __restrict__ bd1, ushort_t* __restrict__ h) {
  extern __shared__ ushort_t smem[];
  int b = blockIdx.x;
  int work = (b & 7) * 128 + (b >> 3);   // bijective (1024 % 8 == 0)
  int m0 = (work >> 4) * 256;
  int n0 = (work & 15) * 128;
  int tid = threadIdx.x, wid = tid >> 6, lane = tid & 63;
  int wm = wid >> 1, wn = wid & 1;
  f32x4 acc[8][4];
  ACC_ZERO(acc, 8, 4);
  pipe_kloop84<256, 128>(x_bf, 1024, m0, Wd1T, 1024, n0, 1024, smem, tid, wm,
                         wn, acc);
  int r = lane & 15, q = lane >> 4;
#pragma unroll
  for (int ni = 0; ni < 4; ++ni) {
    int col = n0 + wn * 64 + ni * 16 + r;
    float bias = bd1[col];
    int e = col >> 8, nn = col & 255;
    ushort_t* hp = h + (size_t)e * 16384 * 256 + nn;
#pragma unroll
    for (int mi = 0; mi < 8; ++mi) {
      int rowb = m0 + wm * 128 + mi * 16 + q * 4;
#pragma unroll
      for (int j = 0; j < 4; ++j) {
        float v = fmaxf(acc[mi][ni][j] + bias, 0.f);
        hp[(size_t)(rowb + j) * 256] = f2bf(v);
      }
    }
  }
}

// ---------------------------------------------------------------------------
// disc_loss: recon = h[e] @ Wd2[e] + bd2[e]; sum((recon-x)^2) -> losses.
// Tile 128x128, K=256 (nt=8).  grid 8192 (e x 128m x 8n), 256 thr;
// expert e -> XCD e; n fastest among dispatch-adjacent blocks (A-tile L2
// reuse -- R12 showed this is critical).  3 blocks/CU.
// ---------------------------------------------------------------------------
__global__ __launch_bounds__(THREADS, 3) void disc_loss_kernel(
    const ushort_t* __restrict__ h, const ushort_t* __restrict__ Wd2T,
    const float* __restrict__ bd2, const ushort_t* __restrict__ x_bf,
    float* __restrict__ losses) {
  extern __shared__ ushort_t smem[];
  __shared__ float red[4];
  int b = blockIdx.x;
  int work = (b & 7) * 1024 + (b >> 3);  // 8192 % 8 == 0
  int e = work >> 10;                    // 1024 works per expert -> one XCD
  int m0 = ((work >> 3) & 127) * 128;
  int n0 = (work & 7) * 128;
  int tid = threadIdx.x, wid = tid >> 6, lane = tid & 63;
  int wm = wid >> 1, wn = wid & 1;
  int r = lane & 15, q = lane >> 4;
  const ushort_t* hA = h + (size_t)e * 16384 * 256;
  const ushort_t* W2 = Wd2T + (size_t)e * 1024 * 256;

  f32x4 acc[4][4];
  ACC_ZERO(acc, 4, 4);
  pipe_kloop44<128, 128>(hA, 256, m0, W2, 256, n0, 256, smem, tid, wm, wn,
                         acc);

  float s = 0.f;
#pragma unroll
  for (int ni = 0; ni < 4; ++ni) {
    int colg = n0 + wn * 64 + ni * 16 + r;
    float bias = bd2[e * 1024 + colg];
#pragma unroll
    for (int mi = 0; mi < 4; ++mi) {
      int rowg = m0 + wm * 64 + mi * 16 + q * 4;
#pragma unroll
      for (int j = 0; j < 4; ++j) {
        float v = acc[mi][ni][j] + bias -
                  bf2f(x_bf[(size_t)(rowg + j) * 1024 + colg]);
        s += v * v;
      }
    }
  }
#pragma unroll
  for (int off = 32; off > 0; off >>= 1) s += __shfl_down(s, off);
  if (lane == 0) red[wid] = s;
  __syncthreads();
  if (tid == 0) {
    float t = red[0] + red[1] + red[2] + red[3];
    atomicAdd(&losses[e * 8 + (m0 >> 11)], t);
  }
}

// ---------------------------------------------------------------------------
// Final: out = x @ W_base + b_base + a @ Wa_up[e] + ba_up[e],
// e = inline argmin(losses[:, sample]).  grid 512 (64m x 8n), 256 thr.
// ---------------------------------------------------------------------------
__global__ __launch_bounds__(THREADS, 2) void final_kernel(
    const ushort_t* __restrict__ x, const ushort_t* __restrict__ WbT,
    const float* __restrict__ b_base, const ushort_t* __restrict__ a,
    const ushort_t* __restrict__ WauT, const float* __restrict__ ba_up,
    const float* __restrict__ losses, float* __restrict__ out) {
  extern __shared__ ushort_t smem[];
  int b = blockIdx.x;
  int work = (b & 7) * 64 + (b >> 3);    // 512 % 8 == 0
  int m0 = (work >> 3) * 256;
  int n0 = (work & 7) * 128;
  int e = argmin8(losses, m0 >> 11);
  int tid = threadIdx.x, wid = tid >> 6, lane = tid & 63;
  int wm = wid >> 1, wn = wid & 1;
  f32x4 acc[8][4];
  ACC_ZERO(acc, 8, 4);
  pipe_kloop84<256, 128>(x, 1024, m0, WbT, 1024, n0, 1024, smem, tid, wm, wn,
                         acc);
  pipe_kloop84<256, 128>(a, 64, m0, WauT + (size_t)e * 1024 * 64, 64, n0, 64,
                         smem, tid, wm, wn, acc);
  int r = lane & 15, q = lane >> 4;
#pragma unroll
  for (int ni = 0; ni < 4; ++ni) {
    int col = n0 + wn * 64 + ni * 16 + r;
    float bias = b_base[col] + ba_up[e * 1024 + col];
#pragma unroll
    for (int mi = 0; mi < 8; ++mi) {
      int rowb = m0 + wm * 128 + mi * 16 + q * 4;
#pragma unroll
      for (int j = 0; j < 4; ++j)
        out[(size_t)(rowb + j) * 1024 + col] = acc[mi][ni][j] + bias;
    }
  }
}

// ===========================================================================
// LEAN PATH (adapter_down): 2-barrier loop, BK=32, 256 threads, tile 64x64,
// grid 256.  e = inline argmin.
// ===========================================================================
__global__ __launch_bounds__(THREADS) void adapter_down_kernel(
    const ushort_t* __restrict__ x, const ushort_t* __restrict__ WadT,
    const float* __restrict__ ba_down, const float* __restrict__ losses,
    ushort_t* __restrict__ a) {
  __shared__ ushort_t As[64 * 32], Bs[64 * 32];
  int m0 = blockIdx.x * 64;
  int e = argmin8(losses, m0 >> 11);
  int tid = threadIdx.x, wid = tid >> 6, lane = tid & 63;
  int r = lane & 15, q = lane >> 4;
  const ushort_t* W = WadT + (size_t)e * 64 * 1024;
  f32x4 acc[4];
#pragma unroll
  for (int ni = 0; ni < 4; ++ni) acc[ni] = (f32x4){0.f, 0.f, 0.f, 0.f};
  for (int k0 = 0; k0 < 1024; k0 += 32) {
#pragma unroll
    for (int p = 0; p < 2; ++p) {
      int c = tid + p * THREADS;
      int row = c >> 2, slot = c & 3;
      int g = slot ^ sw(row);
      if (c < 256)
        gload_lds16(x + (size_t)(m0 + row) * 1024 + k0 + g * 8, As + c * 8);
      else
        gload_lds16(W + (size_t)(row - 64) * 1024 + k0 + g * 8,
                    Bs + (c - 256) * 8);
    }
    __syncthreads();
    bf16x8 af = frag_sw(As, wid * 16 + r, q);
#pragma unroll
    for (int ni = 0; ni < 4; ++ni) {
      bf16x8 bg = frag_sw(Bs, ni * 16 + r, q);
      acc[ni] = __builtin_amdgcn_mfma_f32_16x16x32_bf16(af, bg, acc[ni], 0, 0, 0);
    }
    __syncthreads();
  }
#pragma unroll
  for (int ni = 0; ni < 4; ++ni) {
    int col = ni * 16 + r;
    float bias = ba_down[e * 64 + col];
    int rowb = m0 + wid * 16 + q * 4;
#pragma unroll
    for (int j = 0; j < 4; ++j) {
      float v = fmaxf(acc[ni][j] + bias, 0.f);
      a[(size_t)(rowb + j) * 64 + col] = f2bf(v);
    }
  }
}

// ---------------------------------------------------------------------------
// Host launcher
// ---------------------------------------------------------------------------
extern "C" void kernel_launch(void* const* d_in, const int* in_sizes, int n_in,
                              void* d_out, int out_size, void* d_ws,
                              size_t ws_size, hipStream_t stream) {
  const float* x       = (const float*)d_in[0];
  const float* W_base  = (const float*)d_in[1];
  const float* b_base  = (const float*)d_in[2];
  const float* Wd1     = (const float*)d_in[3];
  const float* bd1     = (const float*)d_in[4];
  const float* Wd2     = (const float*)d_in[5];
  const float* bd2     = (const float*)d_in[6];
  const float* Wa_down = (const float*)d_in[7];
  const float* ba_down = (const float*)d_in[8];
  const float* Wa_up   = (const float*)d_in[9];
  const float* ba_up   = (const float*)d_in[10];
  float* out = (float*)d_out;

  char* w = (char*)d_ws;
  size_t off = 0;
  auto alloc = [&](size_t bytes) {
    void* p = w + off;
    off += (bytes + 255) & ~(size_t)255;
    return p;
  };
  ushort_t* x_bf = (ushort_t*)alloc((size_t)16384 * 1024 * 2);
  ushort_t* Wd1T = (ushort_t*)alloc((size_t)8 * 256 * 1024 * 2);
  ushort_t* Wd2T = (ushort_t*)alloc((size_t)8 * 1024 * 256 * 2);
  ushort_t* WbT  = (ushort_t*)alloc((size_t)1024 * 1024 * 2);
  ushort_t* WadT = (ushort_t*)alloc((size_t)8 * 64 * 1024 * 2);
  ushort_t* WauT = (ushort_t*)alloc((size_t)8 * 1024 * 64 * 2);
  ushort_t* abuf = (ushort_t*)alloc((size_t)16384 * 64 * 2);
  float* losses  = (float*)alloc(64 * 4);
  size_t hbytes = (size_t)8 * 16384 * 256 * 2;  // 67 MB
  ushort_t* h = (ws_size >= off + hbytes) ? (ushort_t*)alloc(hbytes)
                                          : (ushort_t*)d_out;  // out rewritten later

  // dynamic LDS caps (host-side, capture-safe)
  (void)hipFuncSetAttribute((const void*)disc_h_kernel,
                            hipFuncAttributeMaxDynamicSharedMemorySize,
                            PIPE_LDS_BYTES);
  (void)hipFuncSetAttribute((const void*)disc_loss_kernel,
                            hipFuncAttributeMaxDynamicSharedMemorySize,
                            DL_LDS_BYTES);
  (void)hipFuncSetAttribute((const void*)final_kernel,
                            hipFuncAttributeMaxDynamicSharedMemorySize,
                            PIPE_LDS_BYTES);

  // fused prologue: transposes + x cast (+ zero losses)
  transpose_all_kernel<<<8192, dim3(32, 8), 0, stream>>>(
      Wd1, Wd2, W_base, Wa_down, Wa_up, (const float4*)x, Wd1T, Wd2T, WbT,
      WadT, WauT, (ushort4*)x_bf, losses);

  // discriminators
  disc_h_kernel<<<1024, THREADS, PIPE_LDS_BYTES, stream>>>(x_bf, Wd1T, bd1, h);
  disc_loss_kernel<<<8192, THREADS, DL_LDS_BYTES, stream>>>(h, Wd2T, bd2,
                                                            x_bf, losses);

  // adapter + base (argmin inlined from losses)
  adapter_down_kernel<<<256, THREADS, 0, stream>>>(x_bf, WadT, ba_down,
                                                   losses, abuf);
  final_kernel<<<512, THREADS, PIPE_LDS_BYTES, stream>>>(x_bf, WbT, b_base,
                                                         abuf, WauT, ba_up,
                                                         losses, out);
}

// Round 18
// 263.071 us; speedup vs baseline: 1.0586x; 1.0586x over previous
//
#include <hip/hip_runtime.h>

// ---------------------------------------------------------------------------
// Types
// ---------------------------------------------------------------------------
typedef __bf16 bf16x8 __attribute__((ext_vector_type(8)));
typedef float f32x4 __attribute__((ext_vector_type(4)));
typedef unsigned short ushort_t;

#define THREADS 256      // 4-wave path (disc_h / final / adapter_down)
#define PTHREADS 512     // 8-wave path (disc_loss)

__device__ __forceinline__ unsigned short f2bf(float f) {
  unsigned int u = __builtin_bit_cast(unsigned int, f);
  u += 0x7fffu + ((u >> 16) & 1u);   // RNE (no NaN in this data)
  return (unsigned short)(u >> 16);
}

__device__ __forceinline__ float bf2f(ushort_t u) {
  unsigned int v = ((unsigned int)u) << 16;
  return __builtin_bit_cast(float, v);
}

__device__ __forceinline__ void gload_lds16(const ushort_t* g, ushort_t* l) {
  __builtin_amdgcn_global_load_lds(
      (const __attribute__((address_space(1))) void*)g,
      (__attribute__((address_space(3))) void*)l, 16, 0, 0);
}

// counted vmcnt wait. NO sched_barrier (m141/R8 lesson).
template <int N>
__device__ __forceinline__ void wait_vmcnt() {
  if constexpr (N == 0)
    asm volatile("s_waitcnt vmcnt(0)" ::: "memory");
  else if constexpr (N == 3)
    asm volatile("s_waitcnt vmcnt(3)" ::: "memory");
  else if constexpr (N == 6)
    asm volatile("s_waitcnt vmcnt(6)" ::: "memory");
}

__device__ __forceinline__ void block_barrier() {
  asm volatile("" ::: "memory");
  __builtin_amdgcn_s_barrier();
  asm volatile("" ::: "memory");
}

// inline argmin over losses[e*8 + sample], e = 0..7
__device__ __forceinline__ int argmin8(const float* __restrict__ losses,
                                       int sample) {
  float best = losses[sample];
  int bi = 0;
#pragma unroll
  for (int e = 1; e < 8; ++e) {
    float v = losses[e * 8 + sample];
    if (v < best) { best = v; bi = e; }
  }
  return bi;
}

// ---------------------------------------------------------------------------
// Fused prologue: weight transposes + x cast in ONE kernel.  block (32,8).
//   [0,2048)    Wd1  -> Wd1T   [2048,4096) Wd2 -> Wd2T
//   [4096,5120) Wb   -> WbT    [5120,5632) Wad -> WadT
//   [5632,6144) Wau  -> WauT   [6144,8192) cast x (f32 -> bf16)
// Block 0 also zeroes losses[64].
// ---------------------------------------------------------------------------
__global__ void transpose_all_kernel(
    const float* __restrict__ Wd1, const float* __restrict__ Wd2,
    const float* __restrict__ Wb, const float* __restrict__ Wad,
    const float* __restrict__ Wau, const float4* __restrict__ x4,
    ushort_t* __restrict__ Wd1T, ushort_t* __restrict__ Wd2T,
    ushort_t* __restrict__ WbT, ushort_t* __restrict__ WadT,
    ushort_t* __restrict__ WauT, ushort4* __restrict__ x_bf4,
    float* __restrict__ losses) {
  __shared__ float t[32][33];
  int b = blockIdx.x;
  int tx = threadIdx.x, ty = threadIdx.y;
  int ft = ty * 32 + tx;
  if (b == 0 && ft < 64) losses[ft] = 0.f;

  if (b >= 6144) {
    int base = (b - 6144) * 2048 + ft;
#pragma unroll
    for (int i = 0; i < 8; ++i) {
      float4 v = x4[base + i * 256];
      ushort4 o;
      o.x = f2bf(v.x); o.y = f2bf(v.y); o.z = f2bf(v.z); o.w = f2bf(v.w);
      x_bf4[base + i * 256] = o;
    }
    return;
  }

  const float* src;
  ushort_t* dst;
  int R, C, z, cx, ry;
  if (b < 2048) {
    src = Wd1; dst = Wd1T; R = 1024; C = 256;
    z = b >> 8; int rem = b & 255; cx = rem & 7; ry = rem >> 3;
  } else if (b < 4096) {
    int bb = b - 2048;
    src = Wd2; dst = Wd2T; R = 256; C = 1024;
    z = bb >> 8; int rem = bb & 255; cx = rem & 31; ry = rem >> 5;
  } else if (b < 5120) {
    int bb = b - 4096;
    src = Wb; dst = WbT; R = 1024; C = 1024;
    z = 0; cx = bb & 31; ry = bb >> 5;
  } else if (b < 5632) {
    int bb = b - 5120;
    src = Wad; dst = WadT; R = 1024; C = 64;
    z = bb >> 6; int rem = bb & 63; cx = rem & 1; ry = rem >> 1;
  } else {
    int bb = b - 5632;
    src = Wau; dst = WauT; R = 64; C = 1024;
    z = bb >> 6; int rem = bb & 63; cx = rem & 31; ry = rem >> 5;
  }
  size_t zoff = (size_t)z * R * C;
  src += zoff; dst += zoff;
  int c0 = cx * 32, r0 = ry * 32;
#pragma unroll
  for (int i = 0; i < 4; ++i)
    t[ty + 8 * i][tx] = src[(size_t)(r0 + ty + 8 * i) * C + c0 + tx];
  __syncthreads();
#pragma unroll
  for (int i = 0; i < 4; ++i)
    dst[(size_t)(c0 + ty + 8 * i) * R + r0 + tx] = f2bf(t[tx][ty + 8 * i]);
}

#define ACC_ZERO(acc, MM, NN)                        \
  _Pragma("unroll") for (int _i = 0; _i < MM; ++_i)  \
  _Pragma("unroll") for (int _j = 0; _j < NN; ++_j)  \
      acc[_i][_j] = (f32x4){0.f, 0.f, 0.f, 0.f};

// ---------------------------------------------------------------------------
// 4-slot XOR swizzle (R4/R7-proven conflict-free).
// LDS tile [ROWS][32] bf16; slot s of row holds global k-chunk s ^ ((row>>1)&3).
// ---------------------------------------------------------------------------
__device__ __forceinline__ int sw(int row) { return (row >> 1) & 3; }

__device__ __forceinline__ bf16x8 frag_sw(const ushort_t* lds, int row, int q) {
  int slot = q ^ sw(row);
  return *(const bf16x8*)(lds + (row * 4 + slot) * 8);
}

// Staging, templated on block size.  (BM+BN)*4/NT loads per thread per stage.
template <int BM, int BN, int NT>
__device__ __forceinline__ void stage_p(const ushort_t* __restrict__ A,
                                        size_t lda, int arow0,
                                        const ushort_t* __restrict__ BT,
                                        size_t ldb, int brow0, int k0,
                                        ushort_t* As, ushort_t* Bs, int tid) {
#pragma unroll
  for (int i = 0; i < BM * 4 / NT; ++i) {
    int c = tid + i * NT;
    int row = c >> 2, slot = c & 3;
    int g = slot ^ sw(row);
    gload_lds16(A + (size_t)(arow0 + row) * lda + k0 + g * 8, As + c * 8);
  }
#pragma unroll
  for (int i = 0; i < BN * 4 / NT; ++i) {
    int c = tid + i * NT;
    int row = c >> 2, slot = c & 3;
    int g = slot ^ sw(row);
    gload_lds16(BT + (size_t)(brow0 + row) * ldb + k0 + g * 8, Bs + c * 8);
  }
}

#define PIPE_LDS_BYTES ((3 * (256 * 32) + 3 * (128 * 32)) * 2)  // 73728

// ===========================================================================
// PIPE PATH A (disc_h / final): 256 thr = 4 waves (2m x 2n), wave-tile
// 128x64, acc[8][4].  R14-measured best for deep-K (nt>=16).
// Per K-step: vmcnt(6) -> barrier -> stage(t+2) -> ds_read 12 frags ->
// setprio(1) 32 MFMA.
// ===========================================================================
template <int BM, int BN>
__device__ __forceinline__ void pipe_kloop84(const ushort_t* __restrict__ A,
                                             size_t lda, int arow0,
                                             const ushort_t* __restrict__ BT,
                                             size_t ldb, int brow0, int K,
                                             ushort_t* smem, int tid, int wm,
                                             int wn, f32x4 acc[8][4]) {
  constexpr int ASLOT = BM * 32, BSLOT = BN * 32;
  ushort_t* Asl = smem;
  ushort_t* Bsl = smem + 3 * ASLOT;
  int lane = tid & 63;
  int r = lane & 15, q = lane >> 4;
  int nt = K >> 5;
  stage_p<BM, BN, THREADS>(A, lda, arow0, BT, ldb, brow0, 0, Asl, Bsl, tid);
  if (nt > 1)
    stage_p<BM, BN, THREADS>(A, lda, arow0, BT, ldb, brow0, 32, Asl + ASLOT,
                             Bsl + BSLOT, tid);
  for (int t = 0; t < nt; ++t) {
    if (t + 1 < nt)
      wait_vmcnt<6>();
    else
      wait_vmcnt<0>();
    block_barrier();
    if (t + 2 < nt) {
      int s = (t + 2) % 3;
      stage_p<BM, BN, THREADS>(A, lda, arow0, BT, ldb, brow0, (t + 2) * 32,
                               Asl + s * ASLOT, Bsl + s * BSLOT, tid);
    }
    int cur = t % 3;
    const ushort_t* Ac = Asl + cur * ASLOT;
    const ushort_t* Bc = Bsl + cur * BSLOT;
    bf16x8 af[8], bg[4];
#pragma unroll
    for (int mi = 0; mi < 8; ++mi)
      af[mi] = frag_sw(Ac, wm * 128 + mi * 16 + r, q);
#pragma unroll
    for (int ni = 0; ni < 4; ++ni)
      bg[ni] = frag_sw(Bc, wn * 64 + ni * 16 + r, q);
    __builtin_amdgcn_s_setprio(1);
#pragma unroll
    for (int mi = 0; mi < 8; ++mi)
#pragma unroll
      for (int ni = 0; ni < 4; ++ni)
        acc[mi][ni] = __builtin_amdgcn_mfma_f32_16x16x32_bf16(
            af[mi], bg[ni], acc[mi][ni], 0, 0, 0);
    __builtin_amdgcn_s_setprio(0);
  }
  block_barrier();
}

// ===========================================================================
// PIPE PATH B (disc_loss): 512 thr = 8 waves (4m x 2n), wave-tile 64x64,
// acc[4][4].  R13/R16-measured best for short-K (nt=8): 16 waves/CU hide
// the proportionally-large pipeline fill/drain.
// Per K-step: vmcnt(3) -> barrier -> stage(t+2) -> ds_read 8 frags ->
// setprio(1) 16 MFMA.
// ===========================================================================
template <int BM, int BN>
__device__ __forceinline__ void pipe_kloop44(const ushort_t* __restrict__ A,
                                             size_t lda, int arow0,
                                             const ushort_t* __restrict__ BT,
                                             size_t ldb, int brow0, int K,
                                             ushort_t* smem, int tid, int wm,
                                             int wn, f32x4 acc[4][4]) {
  constexpr int ASLOT = BM * 32, BSLOT = BN * 32;
  ushort_t* Asl = smem;
  ushort_t* Bsl = smem + 3 * ASLOT;
  int lane = tid & 63;
  int r = lane & 15, q = lane >> 4;
  int nt = K >> 5;
  stage_p<BM, BN, PTHREADS>(A, lda, arow0, BT, ldb, brow0, 0, Asl, Bsl, tid);
  if (nt > 1)
    stage_p<BM, BN, PTHREADS>(A, lda, arow0, BT, ldb, brow0, 32, Asl + ASLOT,
                              Bsl + BSLOT, tid);
  for (int t = 0; t < nt; ++t) {
    if (t + 1 < nt)
      wait_vmcnt<3>();
    else
      wait_vmcnt<0>();
    block_barrier();
    if (t + 2 < nt) {
      int s = (t + 2) % 3;
      stage_p<BM, BN, PTHREADS>(A, lda, arow0, BT, ldb, brow0, (t + 2) * 32,
                                Asl + s * ASLOT, Bsl + s * BSLOT, tid);
    }
    int cur = t % 3;
    const ushort_t* Ac = Asl + cur * ASLOT;
    const ushort_t* Bc = Bsl + cur * BSLOT;
    bf16x8 af[4], bg[4];
#pragma unroll
    for (int mi = 0; mi < 4; ++mi)
      af[mi] = frag_sw(Ac, wm * 64 + mi * 16 + r, q);
#pragma unroll
    for (int ni = 0; ni < 4; ++ni)
      bg[ni] = frag_sw(Bc, wn * 64 + ni * 16 + r, q);
    __builtin_amdgcn_s_setprio(1);
#pragma unroll
    for (int mi = 0; mi < 4; ++mi)
#pragma unroll
      for (int ni = 0; ni < 4; ++ni)
        acc[mi][ni] = __builtin_amdgcn_mfma_f32_16x16x32_bf16(
            af[mi], bg[ni], acc[mi][ni], 0, 0, 0);
    __builtin_amdgcn_s_setprio(0);
  }
  block_barrier();
}

// ---------------------------------------------------------------------------
// disc_h: h = relu(x @ Wd1_all + bd1_all), M=16384, N=2048, K=1024.
// grid 1024, 256 thr, XCD-chunked.  Output -> h[e][16384][256] (e = col>>8).
// ---------------------------------------------------------------------------
__global__ __launch_bounds__(THREADS, 2) void disc_h_kernel(
    const ushort_t* __restrict__ x_bf, const ushort_t* __restrict__ Wd1T,
    const float* __restrict__ bd1, ushort_t* __restrict__ h) {
  extern __shared__ ushort_t smem[];
  int b = blockIdx.x;
  int work = (b & 7) * 128 + (b >> 3);   // bijective (1024 % 8 == 0)
  int m0 = (work >> 4) * 256;
  int n0 = (work & 15) * 128;
  int tid = threadIdx.x, wid = tid >> 6, lane = tid & 63;
  int wm = wid >> 1, wn = wid & 1;
  f32x4 acc[8][4];
  ACC_ZERO(acc, 8, 4);
  pipe_kloop84<256, 128>(x_bf, 1024, m0, Wd1T, 1024, n0, 1024, smem, tid, wm,
                         wn, acc);
  int r = lane & 15, q = lane >> 4;
#pragma unroll
  for (int ni = 0; ni < 4; ++ni) {
    int col = n0 + wn * 64 + ni * 16 + r;
    float bias = bd1[col];
    int e = col >> 8, nn = col & 255;
    ushort_t* hp = h + (size_t)e * 16384 * 256 + nn;
#pragma unroll
    for (int mi = 0; mi < 8; ++mi) {
      int rowb = m0 + wm * 128 + mi * 16 + q * 4;
#pragma unroll
      for (int j = 0; j < 4; ++j) {
        float v = fmaxf(acc[mi][ni][j] + bias, 0.f);
        hp[(size_t)(rowb + j) * 256] = f2bf(v);
      }
    }
  }
}

// ---------------------------------------------------------------------------
// disc_loss: recon = h[e] @ Wd2[e] + bd2[e]; sum((recon-x)^2) -> losses.
// K=256 (nt=8).  grid 4096 (e x 64m x 8n), 512 thr; expert e -> XCD e;
// n fastest among dispatch-adjacent blocks (A-tile L2 reuse -- R12 lesson).
// ---------------------------------------------------------------------------
__global__ __launch_bounds__(PTHREADS, 4) void disc_loss_kernel(
    const ushort_t* __restrict__ h, const ushort_t* __restrict__ Wd2T,
    const float* __restrict__ bd2, const ushort_t* __restrict__ x_bf,
    float* __restrict__ losses) {
  extern __shared__ ushort_t smem[];
  __shared__ float red[8];
  int b = blockIdx.x;
  int work = (b & 7) * 512 + (b >> 3);   // 4096 % 8 == 0
  int e = work >> 9;                     // 512 works per expert -> one XCD
  int m0 = ((work >> 3) & 63) * 256;
  int n0 = (work & 7) * 128;
  int tid = threadIdx.x, wid = tid >> 6, lane = tid & 63;
  int wm = wid >> 1, wn = wid & 1;
  int r = lane & 15, q = lane >> 4;
  const ushort_t* hA = h + (size_t)e * 16384 * 256;
  const ushort_t* W2 = Wd2T + (size_t)e * 1024 * 256;

  f32x4 acc[4][4];
  ACC_ZERO(acc, 4, 4);
  pipe_kloop44<256, 128>(hA, 256, m0, W2, 256, n0, 256, smem, tid, wm, wn,
                         acc);

  float s = 0.f;
#pragma unroll
  for (int ni = 0; ni < 4; ++ni) {
    int colg = n0 + wn * 64 + ni * 16 + r;
    float bias = bd2[e * 1024 + colg];
#pragma unroll
    for (int mi = 0; mi < 4; ++mi) {
      int rowg = m0 + wm * 64 + mi * 16 + q * 4;
#pragma unroll
      for (int j = 0; j < 4; ++j) {
        float v = acc[mi][ni][j] + bias -
                  bf2f(x_bf[(size_t)(rowg + j) * 1024 + colg]);
        s += v * v;
      }
    }
  }
#pragma unroll
  for (int off = 32; off > 0; off >>= 1) s += __shfl_down(s, off);
  if (lane == 0) red[wid] = s;
  __syncthreads();
  if (tid == 0) {
    float t = 0.f;
#pragma unroll
    for (int i = 0; i < 8; ++i) t += red[i];
    atomicAdd(&losses[e * 8 + (m0 >> 11)], t);
  }
}

// ---------------------------------------------------------------------------
// Final: out = x @ W_base + b_base + a @ Wa_up[e] + ba_up[e],
// e = inline argmin(losses[:, sample]).  grid 512 (64m x 8n), 256 thr.
// ---------------------------------------------------------------------------
__global__ __launch_bounds__(THREADS, 2) void final_kernel(
    const ushort_t* __restrict__ x, const ushort_t* __restrict__ WbT,
    const float* __restrict__ b_base, const ushort_t* __restrict__ a,
    const ushort_t* __restrict__ WauT, const float* __restrict__ ba_up,
    const float* __restrict__ losses, float* __restrict__ out) {
  extern __shared__ ushort_t smem[];
  int b = blockIdx.x;
  int work = (b & 7) * 64 + (b >> 3);    // 512 % 8 == 0
  int m0 = (work >> 3) * 256;
  int n0 = (work & 7) * 128;
  int e = argmin8(losses, m0 >> 11);
  int tid = threadIdx.x, wid = tid >> 6, lane = tid & 63;
  int wm = wid >> 1, wn = wid & 1;
  f32x4 acc[8][4];
  ACC_ZERO(acc, 8, 4);
  pipe_kloop84<256, 128>(x, 1024, m0, WbT, 1024, n0, 1024, smem, tid, wm, wn,
                         acc);
  pipe_kloop84<256, 128>(a, 64, m0, WauT + (size_t)e * 1024 * 64, 64, n0, 64,
                         smem, tid, wm, wn, acc);
  int r = lane & 15, q = lane >> 4;
#pragma unroll
  for (int ni = 0; ni < 4; ++ni) {
    int col = n0 + wn * 64 + ni * 16 + r;
    float bias = b_base[col] + ba_up[e * 1024 + col];
#pragma unroll
    for (int mi = 0; mi < 8; ++mi) {
      int rowb = m0 + wm * 128 + mi * 16 + q * 4;
#pragma unroll
      for (int j = 0; j < 4; ++j)
        out[(size_t)(rowb + j) * 1024 + col] = acc[mi][ni][j] + bias;
    }
  }
}

// ===========================================================================
// LEAN PATH (adapter_down): 2-barrier loop, BK=32, 256 threads, tile 64x64,
// grid 256.  e = inline argmin (argmin kernel eliminated).
// ===========================================================================
__global__ __launch_bounds__(THREADS) void adapter_down_kernel(
    const ushort_t* __restrict__ x, const ushort_t* __restrict__ WadT,
    const float* __restrict__ ba_down, const float* __restrict__ losses,
    ushort_t* __restrict__ a) {
  __shared__ ushort_t As[64 * 32], Bs[64 * 32];
  int m0 = blockIdx.x * 64;
  int e = argmin8(losses, m0 >> 11);
  int tid = threadIdx.x, wid = tid >> 6, lane = tid & 63;
  int r = lane & 15, q = lane >> 4;
  const ushort_t* W = WadT + (size_t)e * 64 * 1024;
  f32x4 acc[4];
#pragma unroll
  for (int ni = 0; ni < 4; ++ni) acc[ni] = (f32x4){0.f, 0.f, 0.f, 0.f};
  for (int k0 = 0; k0 < 1024; k0 += 32) {
#pragma unroll
    for (int p = 0; p < 2; ++p) {
      int c = tid + p * THREADS;
      int row = c >> 2, slot = c & 3;
      int g = slot ^ sw(row);
      if (c < 256)
        gload_lds16(x + (size_t)(m0 + row) * 1024 + k0 + g * 8, As + c * 8);
      else
        gload_lds16(W + (size_t)(row - 64) * 1024 + k0 + g * 8,
                    Bs + (c - 256) * 8);
    }
    __syncthreads();
    bf16x8 af = frag_sw(As, wid * 16 + r, q);
#pragma unroll
    for (int ni = 0; ni < 4; ++ni) {
      bf16x8 bg = frag_sw(Bs, ni * 16 + r, q);
      acc[ni] = __builtin_amdgcn_mfma_f32_16x16x32_bf16(af, bg, acc[ni], 0, 0, 0);
    }
    __syncthreads();
  }
#pragma unroll
  for (int ni = 0; ni < 4; ++ni) {
    int col = ni * 16 + r;
    float bias = ba_down[e * 64 + col];
    int rowb = m0 + wid * 16 + q * 4;
#pragma unroll
    for (int j = 0; j < 4; ++j) {
      float v = fmaxf(acc[ni][j] + bias, 0.f);
      a[(size_t)(rowb + j) * 64 + col] = f2bf(v);
    }
  }
}

// ---------------------------------------------------------------------------
// Host launcher
// ---------------------------------------------------------------------------
extern "C" void kernel_launch(void* const* d_in, const int* in_sizes, int n_in,
                              void* d_out, int out_size, void* d_ws,
                              size_t ws_size, hipStream_t stream) {
  const float* x       = (const float*)d_in[0];
  const float* W_base  = (const float*)d_in[1];
  const float* b_base  = (const float*)d_in[2];
  const float* Wd1     = (const float*)d_in[3];
  const float* bd1     = (const float*)d_in[4];
  const float* Wd2     = (const float*)d_in[5];
  const float* bd2     = (const float*)d_in[6];
  const float* Wa_down = (const float*)d_in[7];
  const float* ba_down = (const float*)d_in[8];
  const float* Wa_up   = (const float*)d_in[9];
  const float* ba_up   = (const float*)d_in[10];
  float* out = (float*)d_out;

  char* w = (char*)d_ws;
  size_t off = 0;
  auto alloc = [&](size_t bytes) {
    void* p = w + off;
    off += (bytes + 255) & ~(size_t)255;
    return p;
  };
  ushort_t* x_bf = (ushort_t*)alloc((size_t)16384 * 1024 * 2);
  ushort_t* Wd1T = (ushort_t*)alloc((size_t)8 * 256 * 1024 * 2);
  ushort_t* Wd2T = (ushort_t*)alloc((size_t)8 * 1024 * 256 * 2);
  ushort_t* WbT  = (ushort_t*)alloc((size_t)1024 * 1024 * 2);
  ushort_t* WadT = (ushort_t*)alloc((size_t)8 * 64 * 1024 * 2);
  ushort_t* WauT = (ushort_t*)alloc((size_t)8 * 1024 * 64 * 2);
  ushort_t* abuf = (ushort_t*)alloc((size_t)16384 * 64 * 2);
  float* losses  = (float*)alloc(64 * 4);
  size_t hbytes = (size_t)8 * 16384 * 256 * 2;  // 67 MB
  ushort_t* h = (ws_size >= off + hbytes) ? (ushort_t*)alloc(hbytes)
                                          : (ushort_t*)d_out;  // out rewritten later

  // allow 72 KB dynamic LDS for the pipelined kernels (host-side, capture-safe)
  (void)hipFuncSetAttribute((const void*)disc_h_kernel,
                            hipFuncAttributeMaxDynamicSharedMemorySize,
                            PIPE_LDS_BYTES);
  (void)hipFuncSetAttribute((const void*)disc_loss_kernel,
                            hipFuncAttributeMaxDynamicSharedMemorySize,
                            PIPE_LDS_BYTES);
  (void)hipFuncSetAttribute((const void*)final_kernel,
                            hipFuncAttributeMaxDynamicSharedMemorySize,
                            PIPE_LDS_BYTES);

  // fused prologue: transposes + x cast (+ zero losses)
  transpose_all_kernel<<<8192, dim3(32, 8), 0, stream>>>(
      Wd1, Wd2, W_base, Wa_down, Wa_up, (const float4*)x, Wd1T, Wd2T, WbT,
      WadT, WauT, (ushort4*)x_bf, losses);

  // discriminators
  disc_h_kernel<<<1024, THREADS, PIPE_LDS_BYTES, stream>>>(x_bf, Wd1T, bd1, h);
  disc_loss_kernel<<<4096, PTHREADS, PIPE_LDS_BYTES, stream>>>(h, Wd2T, bd2,
                                                               x_bf, losses);

  // adapter + base (argmin inlined from losses)
  adapter_down_kernel<<<256, THREADS, 0, stream>>>(x_bf, WadT, ba_down,
                                                   losses, abuf);
  final_kernel<<<512, THREADS, PIPE_LDS_BYTES, stream>>>(x_bf, WbT, b_base,
                                                         abuf, WauT, ba_up,
                                                         losses, out);
}